// Round 4
// baseline (9469.454 us; speedup 1.0000x reference)
//
#include <hip/hip_runtime.h>
#include <cstdint>
#include <cstddef>

#define BB    128
#define TFRM  80
#define DECL  30
#define EE    512
#define FEATD 4096
#define VV    6000
#define VPAD  6016

using frag_ab = __attribute__((ext_vector_type(8))) short;
using frag_cd = __attribute__((ext_vector_type(4))) float;

static __device__ __forceinline__ float sigf(float x)  { return 1.0f / (1.0f + __expf(-x)); }
static __device__ __forceinline__ float tanhf_(float x){ float e = __expf(2.0f * x); return 1.0f - 2.0f / (e + 1.0f); }
static __device__ __forceinline__ unsigned short f2bf_rne(float x) {
    unsigned int u = __float_as_uint(x);
    u += 0x7fffu + ((u >> 16) & 1u);
    return (unsigned short)(u >> 16);
}

// ---------------- init: zero swizzled h buffers, c states, out, barrier ----------------
__global__ void init_zero(unsigned int* h1a, unsigned int* h1b, unsigned int* h2a, unsigned int* h2b,
                          float* c1, float* c2, float* out, int* bar) {
    int i = blockIdx.x * blockDim.x + threadIdx.x;   // 65536 threads
    if (i < 32768) { h1a[i] = 0u; h1b[i] = 0u; h2a[i] = 0u; h2b[i] = 0u; }
    c1[i] = 0.f; c2[i] = 0.f;
    if (i == 0) { out[0] = 0.f; bar[0] = 0; bar[1] = 0; }
}

// ---------------- fp32 -> bf16 (RNE), x4 (row-major, for gemm64 inputs) ----------------
__global__ void f2bf(const float* __restrict__ src, unsigned short* __restrict__ dst, int n4) {
    int i = blockIdx.x * blockDim.x + threadIdx.x;
    if (i >= n4) return;
    float4 v = ((const float4*)src)[i];
    ushort4 o;
    o.x = f2bf_rne(v.x); o.y = f2bf_rne(v.y); o.z = f2bf_rne(v.z); o.w = f2bf_rne(v.w);
    ((ushort4*)dst)[i] = o;
}

// ---------------- frag-swizzle weight builders ----------------
// layout: flat i = ((r16*KF + kf)*64 + lane)*8 + j ; element = W[r16*16 + (lane&15)][kf*32 + (lane>>4)*8 + j]
__global__ void wsw_hh(const float* __restrict__ W, unsigned short* __restrict__ dst) {
    int i = blockIdx.x * blockDim.x + threadIdx.x;   // 2048*512
    int j = i & 7, lane = (i >> 3) & 63, t = i >> 9;
    int kf = t & 15, r16 = t >> 4;
    int row = r16 * 16 + (lane & 15);
    int k = kf * 32 + ((lane >> 4) << 3) + j;
    dst[i] = f2bf_rne(W[(size_t)row * 512 + k]);
}
__global__ void wsw_cat(const float* __restrict__ w_ih2, const float* __restrict__ w_hh2,
                        unsigned short* __restrict__ dst) {
    int i = blockIdx.x * blockDim.x + threadIdx.x;   // 2048*1024
    int j = i & 7, lane = (i >> 3) & 63, t = i >> 9;
    int kf = t & 31, r16 = t >> 5;
    int row = r16 * 16 + (lane & 15);
    int k = kf * 32 + ((lane >> 4) << 3) + j;
    float v = (k < 512) ? w_ih2[(size_t)row * 1024 + 512 + k]
                        : w_hh2[(size_t)row * 512 + (k - 512)];
    dst[i] = f2bf_rne(v);
}
__global__ void wsw_out(const float* __restrict__ w_out, unsigned short* __restrict__ dst) {
    int i = blockIdx.x * blockDim.x + threadIdx.x;   // 6016*512
    int j = i & 7, lane = (i >> 3) & 63, t = i >> 9;
    int kf = t & 15, r16 = t >> 4;
    int row = r16 * 16 + (lane & 15);
    int k = kf * 32 + ((lane >> 4) << 3) + j;
    dst[i] = (row < VV) ? f2bf_rne(w_out[(size_t)row * 512 + k]) : (unsigned short)0;
}

// ---------------- gather decoder word inputs (rows b*29+t), bf16 row-major ----------------
__global__ void xdec_gather(const float* __restrict__ cap, unsigned short* __restrict__ dst, int n4) {
    int i = blockIdx.x * blockDim.x + threadIdx.x;   // 3712*512/4
    if (i >= n4) return;
    int row = i >> 7;
    int c   = (i & 127) * 4;
    int b = row / 29, t = row - b * 29;
    float4 v = *(const float4*)(cap + (size_t)(b * DECL + t) * EE + c);
    ushort4 o;
    o.x = f2bf_rne(v.x); o.y = f2bf_rne(v.y); o.z = f2bf_rne(v.z); o.w = f2bf_rne(v.w);
    ((ushort4*)dst)[i] = o;
}

// ---------------- bias sums ----------------
__global__ void bias_sum(const float* b_ih1, const float* b_hh1, const float* b_ih2, const float* b_hh2,
                         float* bs1, float* bs2) {
    int i = blockIdx.x * blockDim.x + threadIdx.x;   // 2048
    bs1[i] = b_ih1[i] + b_hh1[i];
    bs2[i] = b_ih2[i] + b_hh2[i];
}

// ---------------- argmax over vocab (first-index ties) ----------------
__global__ void argmax_k(const float* __restrict__ oh, int* __restrict__ labels) {
    int row = blockIdx.x;
    const float* p = oh + (size_t)row * VV;
    int lane = threadIdx.x;
    float best = -1e30f; int bi = 0x7fffffff;
    for (int v = lane; v < VV; v += 64) {
        float x = p[v];
        if (x > best) { best = x; bi = v; }
    }
    for (int off = 32; off; off >>= 1) {
        float ob = __shfl_down(best, off);
        int   oi = __shfl_down(bi,   off);
        if (ob > best || (ob == best && oi < bi)) { best = ob; bi = oi; }
    }
    if (lane == 0) labels[row] = bi;
}

// ---------------- generic 64x64 bf16 NT GEMM (for P_enc / P_dec) ----------------
__global__ __launch_bounds__(256) void gemm64(const unsigned short* __restrict__ A, int lda,
                                              const unsigned short* __restrict__ B, int ldb,
                                              float* __restrict__ C, int ldc,
                                              int K, int ntiles) {
    __shared__ unsigned short As[64][40];
    __shared__ unsigned short Bs[64][40];
    int bm = blockIdx.x / ntiles;
    int bn = blockIdx.x % ntiles;
    int tid = threadIdx.x;
    int wave = tid >> 6, lane = tid & 63;

    int srow  = tid >> 2;
    int scol8 = (tid & 3) * 8;
    const unsigned short* Ap = A + (size_t)(bm * 64 + srow) * lda + scol8;
    const unsigned short* Bp = B + (size_t)(bn * 64 + srow) * ldb + scol8;

    frag_cd acc[4] = {};
    int m16 = lane & 15, kg8 = (lane >> 4) * 8;

    for (int k0 = 0; k0 < K; k0 += 32) {
        *(uint4*)&As[srow][scol8] = *(const uint4*)(Ap + k0);
        *(uint4*)&Bs[srow][scol8] = *(const uint4*)(Bp + k0);
        __syncthreads();
        frag_ab bfrag = *(frag_ab*)&Bs[wave * 16 + m16][kg8];
        #pragma unroll
        for (int mt = 0; mt < 4; ++mt) {
            frag_ab afrag = *(frag_ab*)&As[mt * 16 + m16][kg8];
            acc[mt] = __builtin_amdgcn_mfma_f32_16x16x32_bf16(afrag, bfrag, acc[mt], 0, 0, 0);
        }
        __syncthreads();
    }
    int col = bn * 64 + wave * 16 + (lane & 15);
    #pragma unroll
    for (int mt = 0; mt < 4; ++mt) {
        int rbase = bm * 64 + mt * 16 + (lane >> 4) * 4;
        #pragma unroll
        for (int i = 0; i < 4; ++i)
            C[(size_t)(rbase + i) * ldc + col] = acc[mt][i];
    }
}

// ================= persistent recurrence with manual grid barrier =================
struct MegaArgs {
    const unsigned short *whh1, *wcat2, *wout;   // frag-swizzled
    const float *bias1, *bias2, *b_out;
    const float *P_enc, *P_dec;
    unsigned short *h1a, *h1b, *h2a, *h2b;       // frag-swizzled h state
    float *c1, *c2;
    float *logits;
    const int *labels;
    float *out;
    int *bar;       // [0]=count, [1]=generation  (device-scope)
};

#define NGRID 256

// device-scope sense-free barrier; co-residency guaranteed (256 blocks, 4 waves + ~4KB LDS each)
static __device__ __forceinline__ void gsync(int* bar, int& mygen) {
    __syncthreads();
    if (threadIdx.x == 0) {
        __threadfence();   // agent-scope release: flush L1 + write-back L2
        mygen++;
        int t = __hip_atomic_fetch_add(&bar[0], 1, __ATOMIC_ACQ_REL, __HIP_MEMORY_SCOPE_AGENT);
        if (t == NGRID - 1) {
            __hip_atomic_store(&bar[0], 0, __ATOMIC_RELAXED, __HIP_MEMORY_SCOPE_AGENT);
            __hip_atomic_store(&bar[1], mygen, __ATOMIC_RELEASE, __HIP_MEMORY_SCOPE_AGENT);
        } else {
            while (__hip_atomic_load(&bar[1], __ATOMIC_ACQUIRE, __HIP_MEMORY_SCOPE_AGENT) < mygen) {
                __builtin_amdgcn_s_sleep(2);
            }
        }
        __threadfence();   // agent-scope acquire: invalidate stale L1/L2 before re-reading peers' data
    }
    __syncthreads();
}

// one LSTM cell phase: block = (16 e)x(16 batch) tile, wave = gate.
// KF = K/32 (16 for K=512, 32 for K=1024). Weights & h read as coalesced frags.
template<int KF>
static __device__ __forceinline__ void cell_phase(
    const unsigned short* __restrict__ Wsw,
    const unsigned short* __restrict__ Xa,    // swizzled h, k 0..511
    const unsigned short* __restrict__ Xb,    // swizzled h, k 512..1023 (or null)
    const float* __restrict__ P, int pstride,
    const float* __restrict__ bias,
    float* __restrict__ c, unsigned short* __restrict__ hout,
    int et, int bt, float (&gbuf)[4][16][17])
{
    const int tid = threadIdx.x;
    const int w = tid >> 6, lane = tid & 63;
    const unsigned short* Ap = Wsw + ((size_t)(w * 32 + et) * KF) * 512 + lane * 8;
    const unsigned short* Ba = Xa + (size_t)bt * 8192 + lane * 8;
    const unsigned short* Bb = Xb ? Xb + (size_t)bt * 8192 + lane * 8 : (const unsigned short*)0;
    frag_cd acc = {};
    #pragma unroll
    for (int kf = 0; kf < KF; ++kf) {
        frag_ab af = *(const frag_ab*)(Ap + kf * 512);
        frag_ab bf = (kf < 16) ? *(const frag_ab*)(Ba + kf * 512)
                               : *(const frag_ab*)(Bb + (kf - 16) * 512);
        acc = __builtin_amdgcn_mfma_f32_16x16x32_bf16(af, bf, acc, 0, 0, 0);
    }
    {
        int er = (lane >> 4) * 4, cb = lane & 15;
        #pragma unroll
        for (int i = 0; i < 4; ++i) gbuf[w][er + i][cb] = acc[i];
    }
    __syncthreads();
    {
        int e = tid & 15, b = tid >> 4;
        int row = et * 16 + e, bg = bt * 16 + b;
        float gi = gbuf[0][e][b] + bias[row];
        float gf = gbuf[1][e][b] + bias[EE + row];
        float gg = gbuf[2][e][b] + bias[2 * EE + row];
        float go = gbuf[3][e][b] + bias[3 * EE + row];
        if (P) {
            const float* pp = P + (size_t)bg * pstride;
            gi += pp[row]; gf += pp[EE + row]; gg += pp[2 * EE + row]; go += pp[3 * EE + row];
        }
        size_t ci = (size_t)bg * EE + row;
        float cn = sigf(gf) * c[ci] + sigf(gi) * tanhf_(gg);
        float hn = sigf(go) * tanhf_(cn);
        c[ci] = cn;
        // swizzled h write: element (bg,row) -> bt*8192 + (row/32)*512 + lane'*8 + j
        int kf = row >> 5, kj = row & 31;
        int slane = b + ((kj >> 3) << 4);
        hout[(size_t)bt * 8192 + kf * 512 + slane * 8 + (kj & 7)] = f2bf_rne(hn);
    }
    __syncthreads();
}

// logits tile phase: wave computes vocab tiles vt = et*4+w+128j for its batch tile
static __device__ __forceinline__ void logits_phase(
    const unsigned short* __restrict__ Wosw, const unsigned short* __restrict__ h2sw,
    const float* __restrict__ b_out, float* __restrict__ logits, int et, int bt)
{
    int tid = threadIdx.x, w = tid >> 6, lane = tid & 63;
    frag_ab hb[16];
    const unsigned short* Bp = h2sw + (size_t)bt * 8192 + lane * 8;
    #pragma unroll
    for (int kf = 0; kf < 16; ++kf) hb[kf] = *(const frag_ab*)(Bp + kf * 512);
    for (int j = 0; j < 3; ++j) {
        int vt = et * 4 + w + 128 * j;
        if (vt >= VPAD / 16) break;              // wave-uniform
        const unsigned short* Ap = Wosw + (size_t)vt * 8192 + lane * 8;
        frag_cd acc = {};
        #pragma unroll
        for (int kf = 0; kf < 16; ++kf) {
            frag_ab af = *(const frag_ab*)(Ap + kf * 512);
            acc = __builtin_amdgcn_mfma_f32_16x16x32_bf16(af, hb[kf], acc, 0, 0, 0);
        }
        int col = bt * 16 + (lane & 15);
        int r0 = vt * 16 + (lane >> 4) * 4;
        #pragma unroll
        for (int i = 0; i < 4; ++i) {
            int vrow = r0 + i;
            float bv = (vrow < VV) ? b_out[vrow] : 0.0f;
            logits[(size_t)col * VPAD + vrow] = acc[i] + bv;
        }
    }
}

// per-batch-row log-softmax NLL (block-uniform; called by blocks 0..127)
static __device__ __forceinline__ void loss_phase(
    const float* __restrict__ logits, const int* __restrict__ labels,
    int tcol, float* __restrict__ out, float (&red)[256])
{
    int b = blockIdx.x, tid = threadIdx.x;
    const float* lg = logits + (size_t)b * VPAD;
    float mx = -1e30f;
    for (int v = tid; v < VV; v += 256) mx = fmaxf(mx, lg[v]);
    red[tid] = mx; __syncthreads();
    for (int s = 128; s; s >>= 1) {
        if (tid < s) red[tid] = fmaxf(red[tid], red[tid + s]);
        __syncthreads();
    }
    mx = red[0]; __syncthreads();
    float sm = 0.f;
    for (int v = tid; v < VV; v += 256) sm += __expf(lg[v] - mx);
    red[tid] = sm; __syncthreads();
    for (int s = 128; s; s >>= 1) {
        if (tid < s) red[tid] += red[tid + s];
        __syncthreads();
    }
    if (tid == 0) {
        int lab = labels[b * DECL + tcol];
        atomicAdd(out, (mx + __logf(red[0]) - lg[lab]) * (1.0f / BB));
    }
    __syncthreads();
}

__global__ __launch_bounds__(256, 1) void recurrence_k(MegaArgs a) {
    __shared__ float gbuf[4][16][17];
    __shared__ float red[256];
    const int et = blockIdx.x >> 3, bt = blockIdx.x & 7;
    int mygen = 0;

    unsigned short *h1r = a.h1a, *h1w = a.h1b, *h2r = a.h2a, *h2w = a.h2b;

    // -------- encoder: 80 steps, 2 grid syncs each --------
    for (int t = 0; t < TFRM; ++t) {
        cell_phase<16>(a.whh1, h1r, nullptr, a.P_enc + (size_t)t * 2048, TFRM * 2048,
                       a.bias1, a.c1, h1w, et, bt, gbuf);
        gsync(a.bar, mygen);
        cell_phase<32>(a.wcat2, h1w, h2r, nullptr, 0,
                       a.bias2, a.c2, h2w, et, bt, gbuf);
        { unsigned short* tmp = h1r; h1r = h1w; h1w = tmp; }
        { unsigned short* tmp = h2r; h2r = h2w; h2w = tmp; }
        gsync(a.bar, mygen);
    }

    // -------- decoder lstm1(0) --------
    cell_phase<16>(a.whh1, h1r, nullptr, nullptr, 0, a.bias1, a.c1, h1w, et, bt, gbuf);
    { unsigned short* tmp = h1r; h1r = h1w; h1w = tmp; }
    gsync(a.bar, mygen);

    // -------- decoder: 29 steps, software-pipelined, 2 grid syncs each --------
    for (int t = 0; t < DECL - 1; ++t) {
        // phase X: lstm2(t)  ||  loss(t-1)
        cell_phase<32>(a.wcat2, h1r, h2r, a.P_dec + (size_t)t * 2048, (DECL - 1) * 2048,
                       a.bias2, a.c2, h2w, et, bt, gbuf);
        if (t > 0 && blockIdx.x < BB) loss_phase(a.logits, a.labels, t, a.out, red);
        { unsigned short* tmp = h2r; h2r = h2w; h2w = tmp; }
        gsync(a.bar, mygen);
        // phase Y: logits(t)  ||  lstm1(t+1)
        logits_phase(a.wout, h2r, a.b_out, a.logits, et, bt);
        if (t < DECL - 2) {
            cell_phase<16>(a.whh1, h1r, nullptr, nullptr, 0, a.bias1, a.c1, h1w, et, bt, gbuf);
            { unsigned short* tmp = h1r; h1r = h1w; h1w = tmp; }
        }
        gsync(a.bar, mygen);
    }
    // trailing loss(28)
    if (blockIdx.x < BB) loss_phase(a.logits, a.labels, DECL - 1, a.out, red);
}

extern "C" void kernel_launch(void* const* d_in, const int* in_sizes, int n_in,
                              void* d_out, int out_size, void* d_ws, size_t ws_size,
                              hipStream_t stream) {
    const float* feat    = (const float*)d_in[0];
    const float* caption = (const float*)d_in[1];
    const float* onehot  = (const float*)d_in[2];
    const float* w_ih1   = (const float*)d_in[3];
    const float* w_hh1   = (const float*)d_in[4];
    const float* b_ih1   = (const float*)d_in[5];
    const float* b_hh1   = (const float*)d_in[6];
    const float* w_ih2   = (const float*)d_in[7];
    const float* w_hh2   = (const float*)d_in[8];
    const float* b_ih2   = (const float*)d_in[9];
    const float* b_hh2   = (const float*)d_in[10];
    const float* w_out   = (const float*)d_in[11];
    const float* b_out   = (const float*)d_in[12];
    float* out = (float*)d_out;

    char* ws = (char*)d_ws;
    size_t off = 0;
    auto alloc = [&](size_t bytes) -> char* {
        char* p = ws + off;
        off = (off + bytes + 255) & ~(size_t)255;
        return p;
    };
    unsigned short* feat_bf  = (unsigned short*)alloc((size_t)BB * TFRM * FEATD * 2);  // 83.9 MB
    unsigned short* wih1_bf  = (unsigned short*)alloc((size_t)2048 * FEATD * 2);       // 16.8 MB
    unsigned short* wih2_bf  = (unsigned short*)alloc((size_t)2048 * 1024 * 2);        // 4.2 MB
    unsigned short* whh1_sw  = (unsigned short*)alloc((size_t)2048 * EE * 2);          // 2.1 MB
    unsigned short* wcat2_sw = (unsigned short*)alloc((size_t)2048 * 1024 * 2);        // 4.2 MB
    unsigned short* wout_sw  = (unsigned short*)alloc((size_t)VPAD * EE * 2);          // 6.2 MB
    float* P_enc = (float*)alloc((size_t)BB * TFRM * 2048 * 4);                        // 83.9 MB
    float* P_dec = (float*)alloc((size_t)BB * (DECL - 1) * 2048 * 4);                  // 30.4 MB
    unsigned short* xdec_bf = (unsigned short*)alloc((size_t)BB * (DECL - 1) * EE * 2);
    unsigned short* h1a = (unsigned short*)alloc((size_t)BB * EE * 2);
    unsigned short* h1b = (unsigned short*)alloc((size_t)BB * EE * 2);
    unsigned short* h2a = (unsigned short*)alloc((size_t)BB * EE * 2);
    unsigned short* h2b = (unsigned short*)alloc((size_t)BB * EE * 2);
    float* C1 = (float*)alloc((size_t)BB * EE * 4);
    float* C2 = (float*)alloc((size_t)BB * EE * 4);
    float* logits = (float*)alloc((size_t)BB * VPAD * 4);
    float* bias1 = (float*)alloc(2048 * 4);
    float* bias2 = (float*)alloc(2048 * 4);
    int* labels = (int*)alloc((size_t)BB * DECL * 4);
    int* bar    = (int*)alloc(256);
    if (off > ws_size) return;  // fail loudly (out stays poisoned)

    init_zero<<<256, 256, 0, stream>>>((unsigned int*)h1a, (unsigned int*)h1b,
                                       (unsigned int*)h2a, (unsigned int*)h2b, C1, C2, out, bar);
    f2bf<<<40960, 256, 0, stream>>>(feat, feat_bf, BB * TFRM * FEATD / 4);
    f2bf<<<8192, 256, 0, stream>>>(w_ih1, wih1_bf, 2048 * FEATD / 4);
    f2bf<<<2048, 256, 0, stream>>>(w_ih2, wih2_bf, 2048 * 1024 / 4);
    wsw_hh<<<4096, 256, 0, stream>>>(w_hh1, whh1_sw);
    wsw_cat<<<8192, 256, 0, stream>>>(w_ih2, w_hh2, wcat2_sw);
    wsw_out<<<12032, 256, 0, stream>>>(w_out, wout_sw);
    xdec_gather<<<1856, 256, 0, stream>>>(caption, xdec_bf, BB * (DECL - 1) * EE / 4);
    bias_sum<<<8, 256, 0, stream>>>(b_ih1, b_hh1, b_ih2, b_hh2, bias1, bias2);
    argmax_k<<<BB * DECL, 64, 0, stream>>>(onehot, labels);

    // P_enc[(b*80+t), 2048] = feat @ w_ih1^T
    gemm64<<<160 * 32, 256, 0, stream>>>(feat_bf, FEATD, wih1_bf, FEATD, P_enc, 2048,
                                         FEATD, 32);
    // P_dec[(b*29+t), 2048] = x_word @ w_ih2[:, :512]^T
    gemm64<<<58 * 32, 256, 0, stream>>>(xdec_bf, EE, wih2_bf, 1024, P_dec, 2048,
                                        EE, 32);

    MegaArgs ka;
    ka.whh1 = whh1_sw; ka.wcat2 = wcat2_sw; ka.wout = wout_sw;
    ka.bias1 = bias1; ka.bias2 = bias2; ka.b_out = b_out;
    ka.P_enc = P_enc; ka.P_dec = P_dec;
    ka.h1a = h1a; ka.h1b = h1b; ka.h2a = h2a; ka.h2b = h2b;
    ka.c1 = C1; ka.c2 = C2;
    ka.logits = logits; ka.labels = labels; ka.out = out;
    ka.bar = bar;
    recurrence_k<<<NGRID, 256, 0, stream>>>(ka);
}